// Round 1
// baseline (1162.566 us; speedup 1.0000x reference)
//
#include <hip/hip_runtime.h>
#include <math.h>

#define T_LEN   2048
#define D_MODEL 1024
#define NH      16
#define DH      64
#define DFF     4096
#define NCB     4
#define CDIM    64

// ---------------------------------------------------------------------------
// RMS over rows with optional weight, silu, residual.  out = f(rms(in)*w)+res
// ---------------------------------------------------------------------------
__global__ __launch_bounds__(256) void rms_act_kernel(
    const float* __restrict__ in, const float* __restrict__ res,
    const float* __restrict__ w, float* __restrict__ out,
    int width, int do_silu) {
  int row = blockIdx.x;
  int tid = threadIdx.x;
  const float* rp = in + (size_t)row * width;
  int nv = width >> 10;  // width / (256*4)
  float4 vals[4];
  float ss = 0.f;
  for (int v = 0; v < nv; ++v) {
    float4 xv = reinterpret_cast<const float4*>(rp)[v * 256 + tid];
    vals[v] = xv;
    ss += xv.x * xv.x + xv.y * xv.y + xv.z * xv.z + xv.w * xv.w;
  }
  for (int off = 32; off; off >>= 1) ss += __shfl_down(ss, off, 64);
  __shared__ float wsum[4];
  int wid = tid >> 6, lane = tid & 63;
  if (lane == 0) wsum[wid] = ss;
  __syncthreads();
  if (tid == 0) wsum[0] = wsum[0] + wsum[1] + wsum[2] + wsum[3];
  __syncthreads();
  float scale = rsqrtf(wsum[0] / (float)width + 1e-6f);
  for (int v = 0; v < nv; ++v) {
    int c4 = v * 256 + tid;
    float4 xv = vals[v];
    float4 o;
    o.x = xv.x * scale; o.y = xv.y * scale; o.z = xv.z * scale; o.w = xv.w * scale;
    if (w) {
      float4 wv = reinterpret_cast<const float4*>(w)[c4];
      o.x *= wv.x; o.y *= wv.y; o.z *= wv.z; o.w *= wv.w;
    }
    if (do_silu) {
      o.x = o.x / (1.f + expf(-o.x));
      o.y = o.y / (1.f + expf(-o.y));
      o.z = o.z / (1.f + expf(-o.z));
      o.w = o.w / (1.f + expf(-o.w));
    }
    if (res) {
      float4 rv = reinterpret_cast<const float4*>(res + (size_t)row * width)[c4];
      o.x += rv.x; o.y += rv.y; o.z += rv.z; o.w += rv.w;
    }
    reinterpret_cast<float4*>(out + (size_t)row * width)[c4] = o;
  }
}

// ---------------------------------------------------------------------------
// NT GEMM: C[M,N] = A[M,K] * B[N,K]^T (+RES).  64x64 tile, BK=16, 256 thr.
// ---------------------------------------------------------------------------
__global__ __launch_bounds__(256) void gemm_nt_kernel(
    const float* __restrict__ A, const float* __restrict__ B,
    const float* __restrict__ RES, float* __restrict__ C,
    int M, int N, int K) {
  __shared__ float As[16][68];
  __shared__ float Bs[16][68];
  float4 (*As4)[17] = reinterpret_cast<float4(*)[17]>(As);
  float4 (*Bs4)[17] = reinterpret_cast<float4(*)[17]>(Bs);
  int tid = threadIdx.x;
  int tx = tid & 15, ty = tid >> 4;
  int row0 = blockIdx.y * 64, col0 = blockIdx.x * 64;
  int lm = tid >> 2, lk = (tid & 3) * 4;
  const float* aptr = A + (size_t)(row0 + lm) * K + lk;
  const float* bptr = B + (size_t)(col0 + lm) * K + lk;
  float acc[4][4] = {};
  for (int k0 = 0; k0 < K; k0 += 16) {
    float4 av = *reinterpret_cast<const float4*>(aptr + k0);
    float4 bv = *reinterpret_cast<const float4*>(bptr + k0);
    As[lk + 0][lm] = av.x; As[lk + 1][lm] = av.y;
    As[lk + 2][lm] = av.z; As[lk + 3][lm] = av.w;
    Bs[lk + 0][lm] = bv.x; Bs[lk + 1][lm] = bv.y;
    Bs[lk + 2][lm] = bv.z; Bs[lk + 3][lm] = bv.w;
    __syncthreads();
#pragma unroll
    for (int kk = 0; kk < 16; ++kk) {
      float4 a4 = As4[kk][ty];
      float4 b4 = Bs4[kk][tx];
      float a[4] = {a4.x, a4.y, a4.z, a4.w};
      float b[4] = {b4.x, b4.y, b4.z, b4.w};
#pragma unroll
      for (int i = 0; i < 4; ++i)
#pragma unroll
        for (int j = 0; j < 4; ++j) acc[i][j] = fmaf(a[i], b[j], acc[i][j]);
    }
    __syncthreads();
  }
#pragma unroll
  for (int i = 0; i < 4; ++i) {
    int r = row0 + ty * 4 + i;
    size_t off = (size_t)r * N + col0 + tx * 4;
    float4 o = make_float4(acc[i][0], acc[i][1], acc[i][2], acc[i][3]);
    if (RES) {
      float4 rv = *reinterpret_cast<const float4*>(RES + off);
      o.x += rv.x; o.y += rv.y; o.z += rv.z; o.w += rv.w;
    }
    *reinterpret_cast<float4*>(C + off) = o;
  }
}

// ---------------------------------------------------------------------------
// NN GEMM (down proj): C[:, h*64+c] = A[M,K] * B[h][K,64].  grid.z = h
// ---------------------------------------------------------------------------
__global__ __launch_bounds__(256) void gemm_nn_kernel(
    const float* __restrict__ A, const float* __restrict__ B,
    float* __restrict__ C, int M, int ldc, int K) {
  int h = blockIdx.z;
  B += (size_t)h * K * 64;
  C += h * 64;
  __shared__ float As[16][68];
  __shared__ float Bs[16][68];
  float4 (*As4)[17] = reinterpret_cast<float4(*)[17]>(As);
  float4 (*Bs4)[17] = reinterpret_cast<float4(*)[17]>(Bs);
  int tid = threadIdx.x;
  int tx = tid & 15, ty = tid >> 4;
  int row0 = blockIdx.y * 64;
  int lm = tid >> 2, lk = (tid & 3) * 4;          // A load mapping
  int lbk = tid >> 4, lbc = (tid & 15) * 4;       // B load mapping
  const float* aptr = A + (size_t)(row0 + lm) * K + lk;
  float acc[4][4] = {};
  for (int k0 = 0; k0 < K; k0 += 16) {
    float4 av = *reinterpret_cast<const float4*>(aptr + k0);
    float4 bv = *reinterpret_cast<const float4*>(B + (size_t)(k0 + lbk) * 64 + lbc);
    As[lk + 0][lm] = av.x; As[lk + 1][lm] = av.y;
    As[lk + 2][lm] = av.z; As[lk + 3][lm] = av.w;
    *reinterpret_cast<float4*>(&Bs[lbk][lbc]) = bv;
    __syncthreads();
#pragma unroll
    for (int kk = 0; kk < 16; ++kk) {
      float4 a4 = As4[kk][ty];
      float4 b4 = Bs4[kk][tx];
      float a[4] = {a4.x, a4.y, a4.z, a4.w};
      float b[4] = {b4.x, b4.y, b4.z, b4.w};
#pragma unroll
      for (int i = 0; i < 4; ++i)
#pragma unroll
        for (int j = 0; j < 4; ++j) acc[i][j] = fmaf(a[i], b[j], acc[i][j]);
    }
    __syncthreads();
  }
#pragma unroll
  for (int i = 0; i < 4; ++i) {
    int r = row0 + ty * 4 + i;
    *reinterpret_cast<float4*>(C + (size_t)r * ldc + tx * 4) =
        make_float4(acc[i][0], acc[i][1], acc[i][2], acc[i][3]);
  }
}

// ---------------------------------------------------------------------------
// cache up-proj + product over 4 blocks: G[t,o] = prod_h dot64(Acoef[t,h,:], UP[h,o,:])
// ---------------------------------------------------------------------------
__global__ __launch_bounds__(256) void cache_up_kernel(
    const float* __restrict__ A,   // (T, 256) = (T, 4, 64)
    const float* __restrict__ UP,  // (4, N, 64)
    float* __restrict__ G, int N) {
  __shared__ float As[64][68];
  __shared__ float Bs[64][68];
  float4 (*As4)[17] = reinterpret_cast<float4(*)[17]>(As);
  float4 (*Bs4)[17] = reinterpret_cast<float4(*)[17]>(Bs);
  int tid = threadIdx.x;
  int tx = tid & 15, ty = tid >> 4;
  int row0 = blockIdx.y * 64, col0 = blockIdx.x * 64;
  int lm = tid >> 2, lkq = (tid & 3) * 4;
  float prod[4][4];
#pragma unroll
  for (int i = 0; i < 4; ++i)
#pragma unroll
    for (int j = 0; j < 4; ++j) prod[i][j] = 1.f;
  for (int h = 0; h < 4; ++h) {
    __syncthreads();
#pragma unroll
    for (int s = 0; s < 4; ++s) {
      int k = lkq + 16 * s;
      float4 av = *reinterpret_cast<const float4*>(
          A + (size_t)(row0 + lm) * 256 + h * 64 + k);
      float4 bv = *reinterpret_cast<const float4*>(
          UP + ((size_t)h * N + col0 + lm) * 64 + k);
      As[k + 0][lm] = av.x; As[k + 1][lm] = av.y;
      As[k + 2][lm] = av.z; As[k + 3][lm] = av.w;
      Bs[k + 0][lm] = bv.x; Bs[k + 1][lm] = bv.y;
      Bs[k + 2][lm] = bv.z; Bs[k + 3][lm] = bv.w;
    }
    __syncthreads();
    float dacc[4][4] = {};
#pragma unroll
    for (int kk = 0; kk < 64; ++kk) {
      float4 a4 = As4[kk][ty];
      float4 b4 = Bs4[kk][tx];
      float a[4] = {a4.x, a4.y, a4.z, a4.w};
      float b[4] = {b4.x, b4.y, b4.z, b4.w};
#pragma unroll
      for (int i = 0; i < 4; ++i)
#pragma unroll
        for (int j = 0; j < 4; ++j) dacc[i][j] = fmaf(a[i], b[j], dacc[i][j]);
    }
#pragma unroll
    for (int i = 0; i < 4; ++i)
#pragma unroll
      for (int j = 0; j < 4; ++j) prod[i][j] *= dacc[i][j];
  }
#pragma unroll
  for (int i = 0; i < 4; ++i) {
    int r = row0 + ty * 4 + i;
    *reinterpret_cast<float4*>(G + (size_t)r * N + col0 + tx * 4) =
        make_float4(prod[i][0], prod[i][1], prod[i][2], prod[i][3]);
  }
}

// ---------------------------------------------------------------------------
// RoPE in place on q and k.  Interleaved pairs, theta=10000.
// ---------------------------------------------------------------------------
__global__ __launch_bounds__(256) void rope_kernel(float* __restrict__ q,
                                                   float* __restrict__ k) {
  int t = blockIdx.x;
  int tid = threadIdx.x;
  const float NEG = -0.28782313662425573f;  // -ln(10000)/32
  for (int p = tid; p < 512; p += 256) {
    int i = p & 31;
    int col = (p >> 5) * 64 + 2 * i;
    float ang = (float)t * expf(NEG * (float)i);
    float sv, cv;
    __sincosf(ang, &sv, &cv);
    size_t idx = (size_t)t * D_MODEL + col;
    float q1 = q[idx], q2 = q[idx + 1];
    q[idx]     = q1 * cv - q2 * sv;
    q[idx + 1] = q1 * sv + q2 * cv;
    float k1 = k[idx], k2 = k[idx + 1];
    k[idx]     = k1 * cv - k2 * sv;
    k[idx + 1] = k1 * sv + k2 * cv;
  }
}

// ---------------------------------------------------------------------------
// Flash attention, causal.  BQ=BK=32, dh=64, f32.  grid (T/32, H), 256 thr.
// ---------------------------------------------------------------------------
__global__ __launch_bounds__(256) void attn_kernel(
    const float* __restrict__ Q, const float* __restrict__ K,
    const float* __restrict__ V, float* __restrict__ O) {
  __shared__ float qs[32][68], ks[32][68], vs[32][68], ps[32][33];
  float4 (*qs4)[17] = reinterpret_cast<float4(*)[17]>(qs);
  float4 (*ks4)[17] = reinterpret_cast<float4(*)[17]>(ks);
  float4 (*vs4)[17] = reinterpret_cast<float4(*)[17]>(vs);
  int tid = threadIdx.x;
  int head = blockIdx.y;
  int q0 = blockIdx.x * 32;
  int qi = tid >> 3, sub = tid & 7;
  int lr = tid >> 3, lc = (tid & 7) * 8;  // tile-load mapping
  {
    const float* gp = Q + (size_t)(q0 + lr) * D_MODEL + head * 64 + lc;
    float4 v0 = *reinterpret_cast<const float4*>(gp);
    float4 v1 = *reinterpret_cast<const float4*>(gp + 4);
    qs[lr][lc + 0] = v0.x; qs[lr][lc + 1] = v0.y; qs[lr][lc + 2] = v0.z; qs[lr][lc + 3] = v0.w;
    qs[lr][lc + 4] = v1.x; qs[lr][lc + 5] = v1.y; qs[lr][lc + 6] = v1.z; qs[lr][lc + 7] = v1.w;
  }
  float m_prev = -INFINITY, l = 0.f;
  float acc[8] = {};
  int qg = q0 + qi;
  for (int jt = 0; jt <= (int)blockIdx.x; ++jt) {
    int j0 = jt * 32;
    __syncthreads();
    {
      const float* gk = K + (size_t)(j0 + lr) * D_MODEL + head * 64 + lc;
      const float* gv = V + (size_t)(j0 + lr) * D_MODEL + head * 64 + lc;
      float4 k0v = *reinterpret_cast<const float4*>(gk);
      float4 k1v = *reinterpret_cast<const float4*>(gk + 4);
      float4 v0v = *reinterpret_cast<const float4*>(gv);
      float4 v1v = *reinterpret_cast<const float4*>(gv + 4);
      ks[lr][lc + 0] = k0v.x; ks[lr][lc + 1] = k0v.y; ks[lr][lc + 2] = k0v.z; ks[lr][lc + 3] = k0v.w;
      ks[lr][lc + 4] = k1v.x; ks[lr][lc + 5] = k1v.y; ks[lr][lc + 6] = k1v.z; ks[lr][lc + 7] = k1v.w;
      vs[lr][lc + 0] = v0v.x; vs[lr][lc + 1] = v0v.y; vs[lr][lc + 2] = v0v.z; vs[lr][lc + 3] = v0v.w;
      vs[lr][lc + 4] = v1v.x; vs[lr][lc + 5] = v1v.y; vs[lr][lc + 6] = v1v.z; vs[lr][lc + 7] = v1v.w;
    }
    __syncthreads();
    // ---- S = q k^T, 4 kj per thread (kj = sub + 8*jj)
    float s[4] = {0.f, 0.f, 0.f, 0.f};
#pragma unroll
    for (int dq = 0; dq < 16; ++dq) {
      float4 q4 = qs4[qi][dq];
#pragma unroll
      for (int jj = 0; jj < 4; ++jj) {
        float4 k4 = ks4[sub + 8 * jj][dq];
        s[jj] = fmaf(q4.x, k4.x, s[jj]);
        s[jj] = fmaf(q4.y, k4.y, s[jj]);
        s[jj] = fmaf(q4.z, k4.z, s[jj]);
        s[jj] = fmaf(q4.w, k4.w, s[jj]);
      }
    }
    float mt = -INFINITY;
#pragma unroll
    for (int jj = 0; jj < 4; ++jj) {
      s[jj] *= 0.125f;
      int kg = j0 + sub + 8 * jj;
      if (kg > qg) s[jj] = -INFINITY;
      mt = fmaxf(mt, s[jj]);
    }
    mt = fmaxf(mt, __shfl_xor(mt, 1, 64));
    mt = fmaxf(mt, __shfl_xor(mt, 2, 64));
    mt = fmaxf(mt, __shfl_xor(mt, 4, 64));
    float m_new = fmaxf(m_prev, mt);
    float rsc = expf(m_prev - m_new);
    float lsum = 0.f;
    float p[4];
#pragma unroll
    for (int jj = 0; jj < 4; ++jj) {
      p[jj] = expf(s[jj] - m_new);
      lsum += p[jj];
    }
    lsum += __shfl_xor(lsum, 1, 64);
    lsum += __shfl_xor(lsum, 2, 64);
    lsum += __shfl_xor(lsum, 4, 64);
    l = l * rsc + lsum;
    m_prev = m_new;
#pragma unroll
    for (int jj = 0; jj < 4; ++jj) ps[qi][sub + 8 * jj] = p[jj];
#pragma unroll
    for (int c = 0; c < 8; ++c) acc[c] *= rsc;
    __syncthreads();
    // ---- O += P * V   (thread covers d = sub*8 .. +7 for row qi)
#pragma unroll 8
    for (int kj = 0; kj < 32; ++kj) {
      float pv = ps[qi][kj];
      float4 va = vs4[kj][sub * 2];
      float4 vb = vs4[kj][sub * 2 + 1];
      acc[0] = fmaf(pv, va.x, acc[0]); acc[1] = fmaf(pv, va.y, acc[1]);
      acc[2] = fmaf(pv, va.z, acc[2]); acc[3] = fmaf(pv, va.w, acc[3]);
      acc[4] = fmaf(pv, vb.x, acc[4]); acc[5] = fmaf(pv, vb.y, acc[5]);
      acc[6] = fmaf(pv, vb.z, acc[6]); acc[7] = fmaf(pv, vb.w, acc[7]);
    }
  }
  float inv_l = 1.f / l;
  float* op = O + (size_t)(q0 + qi) * D_MODEL + head * 64 + sub * 8;
  *reinterpret_cast<float4*>(op) =
      make_float4(acc[0] * inv_l, acc[1] * inv_l, acc[2] * inv_l, acc[3] * inv_l);
  *reinterpret_cast<float4*>(op + 4) =
      make_float4(acc[4] * inv_l, acc[5] * inv_l, acc[6] * inv_l, acc[7] * inv_l);
}

// ---------------------------------------------------------------------------
extern "C" void kernel_launch(void* const* d_in, const int* in_sizes, int n_in,
                              void* d_out, int out_size, void* d_ws, size_t ws_size,
                              hipStream_t stream) {
  (void)in_sizes; (void)n_in; (void)out_size; (void)ws_size;
  const float* x   = (const float*)d_in[0];
  const float* ln1 = (const float*)d_in[1];
  const float* ln2 = (const float*)d_in[2];
  const float* wq  = (const float*)d_in[3];
  const float* wk  = (const float*)d_in[4];
  const float* wv  = (const float*)d_in[5];
  const float* wo  = (const float*)d_in[6];
  const float* w1d = (const float*)d_in[7];
  const float* w1u = (const float*)d_in[8];
  const float* w2d = (const float*)d_in[9];
  const float* w2u = (const float*)d_in[10];
  float* out = (float*)d_out;
  char* ws = (char*)d_ws;

  const size_t SZ_TD = (size_t)T_LEN * D_MODEL * sizeof(float);  // 8 MB
  float* h    = (float*)(ws);                       // h, then h2
  float* q    = (float*)(ws + SZ_TD);
  float* k    = (float*)(ws + 2 * SZ_TD);
  float* v    = (float*)(ws + 3 * SZ_TD);
  float* ao   = (float*)(ws + 4 * SZ_TD);           // attn out, later g2
  float* x1   = (float*)(ws + 5 * SZ_TD);
  float* abuf = (float*)(ws + 6 * SZ_TD);           // (T,256)
  float* g    = (float*)(ws + 6 * SZ_TD + (size_t)T_LEN * 256 * sizeof(float));

  dim3 b256(256);
  // 1. h = rms(x) * ln1
  rms_act_kernel<<<T_LEN, b256, 0, stream>>>(x, nullptr, ln1, h, D_MODEL, 0);
  // 2. q,k,v projections
  dim3 gqkv(D_MODEL / 64, T_LEN / 64);
  gemm_nt_kernel<<<gqkv, b256, 0, stream>>>(h, wq, nullptr, q, T_LEN, D_MODEL, D_MODEL);
  gemm_nt_kernel<<<gqkv, b256, 0, stream>>>(h, wk, nullptr, k, T_LEN, D_MODEL, D_MODEL);
  gemm_nt_kernel<<<gqkv, b256, 0, stream>>>(h, wv, nullptr, v, T_LEN, D_MODEL, D_MODEL);
  // 3. rope(q,k)
  rope_kernel<<<T_LEN, b256, 0, stream>>>(q, k);
  // 4. attention
  dim3 ga(T_LEN / 32, NH);
  attn_kernel<<<ga, b256, 0, stream>>>(q, k, v, ao);
  // 5. x1 = ao @ wo^T + x
  gemm_nt_kernel<<<gqkv, b256, 0, stream>>>(ao, wo, x, x1, T_LEN, D_MODEL, D_MODEL);
  // 6. h2 = rms(x1) * ln2
  rms_act_kernel<<<T_LEN, b256, 0, stream>>>(x1, nullptr, ln2, h, D_MODEL, 0);
  // 7. down1: abuf[t, h*64+c]
  dim3 gd1(1, T_LEN / 64, NCB);
  gemm_nn_kernel<<<gd1, b256, 0, stream>>>(h, w1d, abuf, T_LEN, NCB * CDIM, D_MODEL);
  // 8. up1 + product -> g
  dim3 gu1(DFF / 64, T_LEN / 64);
  cache_up_kernel<<<gu1, b256, 0, stream>>>(abuf, w1u, g, DFF);
  // 9. s = silu(rms(g)) in place
  rms_act_kernel<<<T_LEN, b256, 0, stream>>>(g, nullptr, nullptr, g, DFF, 1);
  // 10. down2
  gemm_nn_kernel<<<gd1, b256, 0, stream>>>(g, w2d, abuf, T_LEN, NCB * CDIM, DFF);
  // 11. up2 + product -> g2 (reuse ao)
  dim3 gu2(D_MODEL / 64, T_LEN / 64);
  cache_up_kernel<<<gu2, b256, 0, stream>>>(abuf, w2u, ao, D_MODEL);
  // 12. out = x1 + rms(g2)
  rms_act_kernel<<<T_LEN, b256, 0, stream>>>(ao, x1, nullptr, out, D_MODEL, 0);
}

// Round 2
// 395.917 us; speedup vs baseline: 2.9364x; 2.9364x over previous
//
#include <hip/hip_runtime.h>
#include <math.h>
#include <stdint.h>

#define T_LEN   2048
#define D_MODEL 1024
#define NH      16
#define DFF     4096

typedef __attribute__((ext_vector_type(8))) short bf16x8;
typedef __attribute__((ext_vector_type(4))) float f32x4;
typedef __attribute__((ext_vector_type(4))) unsigned short u16x4;
typedef unsigned short u16;

__device__ inline u16 f2b(float x) {
  unsigned int u = __float_as_uint(x);
  unsigned int r = (u + 0x7fffu + ((u >> 16) & 1u)) >> 16;
  return (u16)r;
}
__device__ inline float b2f(u16 h) { return __uint_as_float(((unsigned int)h) << 16); }

typedef const __attribute__((address_space(1))) unsigned int* gas_t;
typedef __attribute__((address_space(3))) unsigned int* las_t;
__device__ inline void gl_lds16(const void* g, void* l) {
  __builtin_amdgcn_global_load_lds((gas_t)g, (las_t)l, 16, 0, 0);
}

#define MFMA16(a, b, c) __builtin_amdgcn_mfma_f32_16x16x32_bf16((a), (b), (c), 0, 0, 0)

// ---------------------------------------------------------------------------
// f32 -> bf16 convert (grid-stride over float4 chunks)
// ---------------------------------------------------------------------------
__global__ __launch_bounds__(256) void conv_bf16_kernel(
    const float* __restrict__ src, u16* __restrict__ dst, int n4) {
  int i = blockIdx.x * 256 + threadIdx.x;
  if (i < n4) {
    float4 v = reinterpret_cast<const float4*>(src)[i];
    u16x4 o = {f2b(v.x), f2b(v.y), f2b(v.z), f2b(v.w)};
    reinterpret_cast<u16x4*>(dst)[i] = o;
  }
}

// ---------------------------------------------------------------------------
// transpose+convert: w[h][K][64] f32 -> wt[h*64+c][K] bf16.  grid (K/64, 4)
// ---------------------------------------------------------------------------
__global__ __launch_bounds__(256) void tr_kernel(
    const float* __restrict__ w, u16* __restrict__ wt, int K) {
  int k0 = blockIdx.x * 64, h = blockIdx.y;
  __shared__ float Ts[64][65];
  int tid = threadIdx.x;
#pragma unroll
  for (int i = 0; i < 4; ++i) {
    int idx = tid + i * 256;
    int r = idx >> 4, c4 = (idx & 15) * 4;
    float4 v = *reinterpret_cast<const float4*>(w + ((size_t)h * K + k0 + r) * 64 + c4);
    Ts[r][c4 + 0] = v.x; Ts[r][c4 + 1] = v.y; Ts[r][c4 + 2] = v.z; Ts[r][c4 + 3] = v.w;
  }
  __syncthreads();
#pragma unroll
  for (int i = 0; i < 4; ++i) {
    int idx = tid + i * 256;
    int c = idx >> 4, k4 = (idx & 15) * 4;
    u16x4 o = {f2b(Ts[k4 + 0][c]), f2b(Ts[k4 + 1][c]), f2b(Ts[k4 + 2][c]), f2b(Ts[k4 + 3][c])};
    *reinterpret_cast<u16x4*>(wt + (size_t)(h * 64 + c) * K + k0 + k4) = o;
  }
}

// ---------------------------------------------------------------------------
// RMS -> bf16 (optional weight / silu).  One row per block, 256 threads.
// ---------------------------------------------------------------------------
template <int NV, bool SILU, bool WEIGHT>
__global__ __launch_bounds__(256) void rms_bf16_kernel(
    const float* __restrict__ in, const float* __restrict__ w,
    u16* __restrict__ out, int width) {
  int row = blockIdx.x, tid = threadIdx.x;
  const float* rp = in + (size_t)row * width;
  float4 vals[NV];
  float ss = 0.f;
#pragma unroll
  for (int v = 0; v < NV; ++v) {
    vals[v] = reinterpret_cast<const float4*>(rp)[v * 256 + tid];
    ss += vals[v].x * vals[v].x + vals[v].y * vals[v].y +
          vals[v].z * vals[v].z + vals[v].w * vals[v].w;
  }
  for (int off = 32; off; off >>= 1) ss += __shfl_down(ss, off, 64);
  __shared__ float wsum[4];
  if ((tid & 63) == 0) wsum[tid >> 6] = ss;
  __syncthreads();
  float tot = wsum[0] + wsum[1] + wsum[2] + wsum[3];
  float scale = rsqrtf(tot / (float)width + 1e-6f);
#pragma unroll
  for (int v = 0; v < NV; ++v) {
    int c4 = v * 256 + tid;
    float o0 = vals[v].x * scale, o1 = vals[v].y * scale,
          o2 = vals[v].z * scale, o3 = vals[v].w * scale;
    if constexpr (WEIGHT) {
      float4 wv = reinterpret_cast<const float4*>(w)[c4];
      o0 *= wv.x; o1 *= wv.y; o2 *= wv.z; o3 *= wv.w;
    }
    if constexpr (SILU) {
      o0 = o0 / (1.f + __expf(-o0)); o1 = o1 / (1.f + __expf(-o1));
      o2 = o2 / (1.f + __expf(-o2)); o3 = o3 / (1.f + __expf(-o3));
    }
    u16x4 ov = {f2b(o0), f2b(o1), f2b(o2), f2b(o3)};
    reinterpret_cast<u16x4*>(out + (size_t)row * width)[c4] = ov;
  }
}

// final: out = res + rms(in), width 1024, f32 out
__global__ __launch_bounds__(256) void rms_add_kernel(
    const float* __restrict__ in, const float* __restrict__ res,
    float* __restrict__ out) {
  int row = blockIdx.x, tid = threadIdx.x;
  const float* rp = in + (size_t)row * D_MODEL;
  float4 v = reinterpret_cast<const float4*>(rp)[tid];
  float ss = v.x * v.x + v.y * v.y + v.z * v.z + v.w * v.w;
  for (int off = 32; off; off >>= 1) ss += __shfl_down(ss, off, 64);
  __shared__ float wsum[4];
  if ((tid & 63) == 0) wsum[tid >> 6] = ss;
  __syncthreads();
  float tot = wsum[0] + wsum[1] + wsum[2] + wsum[3];
  float scale = rsqrtf(tot / (float)D_MODEL + 1e-6f);
  float4 rv = reinterpret_cast<const float4*>(res + (size_t)row * D_MODEL)[tid];
  float4 o = make_float4(v.x * scale + rv.x, v.y * scale + rv.y,
                         v.z * scale + rv.z, v.w * scale + rv.w);
  reinterpret_cast<float4*>(out + (size_t)row * D_MODEL)[tid] = o;
}

// ---------------------------------------------------------------------------
// bf16 NT GEMM core: C[M,N] = A[M,K] * B[N,K]^T.  128x128 tile, BK=32,
// 256 thr = 4 waves (2x2 of 64x64).  global_load_lds + XOR-swizzled LDS.
// ---------------------------------------------------------------------------
template <bool BF16_OUT, bool HAS_RES>
__device__ inline void gemm_nt_body(const u16* A, const u16* B, void* Cv,
                                    const float* RES, int N, int K,
                                    int row0, int col0) {
  __shared__ __align__(16) u16 As[128 * 32];
  __shared__ __align__(16) u16 Bs[128 * 32];
  int tid = threadIdx.x, lane = tid & 63, wid = tid >> 6;
  int wr = wid >> 1, wc = wid & 1;
  const f32x4 fz = {0.f, 0.f, 0.f, 0.f};
  f32x4 acc[4][4];
#pragma unroll
  for (int m = 0; m < 4; ++m)
#pragma unroll
    for (int n = 0; n < 4; ++n) acc[m][n] = fz;

  for (int k0 = 0; k0 < K; k0 += 32) {
    __syncthreads();
#pragma unroll
    for (int i = 0; i < 2; ++i) {
      int wl = wid * 2 + i;
      int row = wl * 16 + (lane >> 2);
      int col8 = ((lane & 3) ^ (row & 3)) * 8;
      gl_lds16(A + (size_t)(row0 + row) * K + k0 + col8, &As[wl * 512]);
      gl_lds16(B + (size_t)(col0 + row) * K + k0 + col8, &Bs[wl * 512]);
    }
    __syncthreads();
    bf16x8 af[4], bfr[4];
#pragma unroll
    for (int m = 0; m < 4; ++m) {
      int r = wr * 64 + m * 16 + (lane & 15);
      af[m] = *reinterpret_cast<const bf16x8*>(&As[r * 32 + (((lane >> 4) ^ (r & 3)) << 3)]);
    }
#pragma unroll
    for (int n = 0; n < 4; ++n) {
      int r = wc * 64 + n * 16 + (lane & 15);
      bfr[n] = *reinterpret_cast<const bf16x8*>(&Bs[r * 32 + (((lane >> 4) ^ (r & 3)) << 3)]);
    }
#pragma unroll
    for (int m = 0; m < 4; ++m)
#pragma unroll
      for (int n = 0; n < 4; ++n) acc[m][n] = MFMA16(af[m], bfr[n], acc[m][n]);
  }
#pragma unroll
  for (int m = 0; m < 4; ++m)
#pragma unroll
    for (int n = 0; n < 4; ++n)
#pragma unroll
      for (int r = 0; r < 4; ++r) {
        int grow = row0 + wr * 64 + m * 16 + (lane >> 4) * 4 + r;
        int gcol = col0 + wc * 64 + n * 16 + (lane & 15);
        float v = acc[m][n][r];
        if constexpr (BF16_OUT) {
          ((u16*)Cv)[(size_t)grow * N + gcol] = f2b(v);
        } else {
          if constexpr (HAS_RES) v += RES[(size_t)grow * N + gcol];
          ((float*)Cv)[(size_t)grow * N + gcol] = v;
        }
      }
}

__global__ __launch_bounds__(256) void gemm_qkv_kernel(
    const u16* __restrict__ A, const u16* Bq, const u16* Bk, const u16* Bv,
    u16* Cq, u16* Ck, u16* Cvp, int K) {
  const u16* B = blockIdx.z == 0 ? Bq : (blockIdx.z == 1 ? Bk : Bv);
  u16* C = blockIdx.z == 0 ? Cq : (blockIdx.z == 1 ? Ck : Cvp);
  gemm_nt_body<true, false>(A, B, C, nullptr, D_MODEL, K, blockIdx.y * 128, blockIdx.x * 128);
}
__global__ __launch_bounds__(256) void gemm_bf16_kernel(
    const u16* __restrict__ A, const u16* __restrict__ B, u16* __restrict__ C,
    int N, int K) {
  gemm_nt_body<true, false>(A, B, C, nullptr, N, K, blockIdx.y * 128, blockIdx.x * 128);
}
__global__ __launch_bounds__(256) void gemm_res_kernel(
    const u16* __restrict__ A, const u16* __restrict__ B, float* __restrict__ C,
    const float* __restrict__ RES, int N, int K) {
  gemm_nt_body<false, true>(A, B, C, RES, N, K, blockIdx.y * 128, blockIdx.x * 128);
}

// ---------------------------------------------------------------------------
// cache up-proj + product: G[t][o] = prod_h dot64(A[t][h*64+:], UP[h][o][:])
// 128x128 tile, K=64 per h.  A:[T][256] bf16, UP:[4][N][64] bf16, G f32.
// ---------------------------------------------------------------------------
__global__ __launch_bounds__(256) void cache_up_mfma(
    const u16* __restrict__ Acoef, const u16* __restrict__ UP,
    float* __restrict__ G, int N) {
  __shared__ __align__(16) u16 As[128 * 64];
  __shared__ __align__(16) u16 Bs[128 * 64];
  int tid = threadIdx.x, lane = tid & 63, wid = tid >> 6;
  int wr = wid >> 1, wc = wid & 1;
  int row0 = blockIdx.y * 128, col0 = blockIdx.x * 128;
  const f32x4 fz = {0.f, 0.f, 0.f, 0.f};
  f32x4 prod[4][4];
#pragma unroll
  for (int m = 0; m < 4; ++m)
#pragma unroll
    for (int n = 0; n < 4; ++n) prod[m][n] = fz + 1.f;

  for (int h = 0; h < 4; ++h) {
    __syncthreads();
#pragma unroll
    for (int i = 0; i < 4; ++i) {
      int wl = wid * 4 + i;
      int row = wl * 8 + (lane >> 3);
      int col8 = ((lane & 7) ^ (row & 7)) * 8;
      gl_lds16(Acoef + (size_t)(row0 + row) * 256 + h * 64 + col8, &As[wl * 512]);
      gl_lds16(UP + ((size_t)h * N + col0 + row) * 64 + col8, &Bs[wl * 512]);
    }
    __syncthreads();
    f32x4 d[4][4];
#pragma unroll
    for (int m = 0; m < 4; ++m)
#pragma unroll
      for (int n = 0; n < 4; ++n) d[m][n] = fz;
#pragma unroll
    for (int kh = 0; kh < 2; ++kh) {
      bf16x8 af[4], bfr[4];
#pragma unroll
      for (int m = 0; m < 4; ++m) {
        int r = wr * 64 + m * 16 + (lane & 15);
        int slot = kh * 4 + (lane >> 4);
        af[m] = *reinterpret_cast<const bf16x8*>(&As[r * 64 + ((slot ^ (r & 7)) << 3)]);
      }
#pragma unroll
      for (int n = 0; n < 4; ++n) {
        int r = wc * 64 + n * 16 + (lane & 15);
        int slot = kh * 4 + (lane >> 4);
        bfr[n] = *reinterpret_cast<const bf16x8*>(&Bs[r * 64 + ((slot ^ (r & 7)) << 3)]);
      }
#pragma unroll
      for (int m = 0; m < 4; ++m)
#pragma unroll
        for (int n = 0; n < 4; ++n) d[m][n] = MFMA16(af[m], bfr[n], d[m][n]);
    }
#pragma unroll
    for (int m = 0; m < 4; ++m)
#pragma unroll
      for (int n = 0; n < 4; ++n) prod[m][n] *= d[m][n];
  }
#pragma unroll
  for (int m = 0; m < 4; ++m)
#pragma unroll
    for (int n = 0; n < 4; ++n)
#pragma unroll
      for (int r = 0; r < 4; ++r) {
        int grow = row0 + wr * 64 + m * 16 + (lane >> 4) * 4 + r;
        int gcol = col0 + wc * 64 + n * 16 + (lane & 15);
        G[(size_t)grow * N + gcol] = prod[m][n][r];
      }
}

// ---------------------------------------------------------------------------
// RoPE in place on bf16 q,k.  One row (t) per block.
// ---------------------------------------------------------------------------
__global__ __launch_bounds__(256) void rope_bf16_kernel(u16* __restrict__ q,
                                                        u16* __restrict__ k) {
  int t = blockIdx.x, tid = threadIdx.x;
  const float NEG = -0.28782313662425573f;  // -ln(10000)/32
#pragma unroll
  for (int u = 0; u < 2; ++u) {
    int p = tid + u * 256;
    int i = p & 31;
    int col = (p >> 5) * 64 + 2 * i;
    float ang = (float)t * __expf(NEG * (float)i);
    float sv, cv;
    __sincosf(ang, &sv, &cv);
    size_t idx = (size_t)t * D_MODEL + col;
    unsigned int* qp = reinterpret_cast<unsigned int*>(q + idx);
    unsigned int qv = *qp;
    float q1 = b2f(qv & 0xffff), q2 = b2f(qv >> 16);
    *qp = (unsigned int)f2b(q1 * cv - q2 * sv) |
          ((unsigned int)f2b(q1 * sv + q2 * cv) << 16);
    unsigned int* kp = reinterpret_cast<unsigned int*>(k + idx);
    unsigned int kv = *kp;
    float k1 = b2f(kv & 0xffff), k2 = b2f(kv >> 16);
    *kp = (unsigned int)f2b(k1 * cv - k2 * sv) |
          ((unsigned int)f2b(k1 * sv + k2 * cv) << 16);
  }
}

// ---------------------------------------------------------------------------
// MFMA flash attention, causal.  64-row Q tile per block, 4 waves (16 q each),
// KV tiles of 64.  Q in regs; K, V^T in swizzled LDS; P via per-wave LDS.
// grid (T/64, NH).
// ---------------------------------------------------------------------------
__global__ __launch_bounds__(256) void attn_mfma_kernel(
    const u16* __restrict__ Q, const u16* __restrict__ Kb,
    const u16* __restrict__ Vb, u16* __restrict__ O) {
  __shared__ __align__(16) u16 Ks[64 * 64];
  __shared__ __align__(16) u16 Vt[64 * 64];
  __shared__ __align__(16) u16 Ps[4][16 * 64];
  int tid = threadIdx.x, lane = tid & 63, wid = tid >> 6;
  int head = blockIdx.y, hoff = head * 64;
  int q0 = blockIdx.x * 64;
  const f32x4 fz = {0.f, 0.f, 0.f, 0.f};

  bf16x8 aq[2];
  {
    int qr = q0 + wid * 16 + (lane & 15);
    const u16* qp = Q + (size_t)qr * D_MODEL + hoff + ((lane >> 4) * 8);
    aq[0] = *reinterpret_cast<const bf16x8*>(qp);
    aq[1] = *reinterpret_cast<const bf16x8*>(qp + 32);
  }
  f32x4 accO[4];
  float m_r[4], l_r[4];
#pragma unroll
  for (int n = 0; n < 4; ++n) accO[n] = fz;
#pragma unroll
  for (int r = 0; r < 4; ++r) { m_r[r] = -INFINITY; l_r[r] = 0.f; }

  int last = blockIdx.x;
  for (int jt = 0; jt <= last; ++jt) {
    int j0 = jt * 64;
    __syncthreads();
    // --- stage K (global_load_lds, pre-swizzled source)
#pragma unroll
    for (int i = 0; i < 2; ++i) {
      int wl = wid * 2 + i;
      int row = wl * 8 + (lane >> 3);
      int col8 = ((lane & 7) ^ (row & 7)) * 8;
      gl_lds16(Kb + (size_t)(j0 + row) * D_MODEL + hoff + col8, &Ks[wl * 512]);
    }
    // --- stage V transposed (reg roundtrip, swizzled scatter)
    bf16x8 vv[2];
    int kk[2], dd8[2];
#pragma unroll
    for (int i = 0; i < 2; ++i) {
      int c = tid + i * 256;
      kk[i] = c >> 3; dd8[i] = (c & 7) * 8;
      vv[i] = *reinterpret_cast<const bf16x8*>(
          Vb + (size_t)(j0 + kk[i]) * D_MODEL + hoff + dd8[i]);
    }
#pragma unroll
    for (int i = 0; i < 2; ++i)
#pragma unroll
      for (int j = 0; j < 8; ++j) {
        int d = dd8[i] + j;
        Vt[d * 64 + (((kk[i] >> 3) ^ (d & 7)) << 3) + (kk[i] & 7)] = (u16)vv[i][j];
      }
    __syncthreads();
    // --- S = Q K^T
    f32x4 s[4];
#pragma unroll
    for (int n = 0; n < 4; ++n) s[n] = fz;
#pragma unroll
    for (int n = 0; n < 4; ++n)
#pragma unroll
      for (int h = 0; h < 2; ++h) {
        int kr = n * 16 + (lane & 15);
        int slot = h * 4 + (lane >> 4);
        bf16x8 bk = *reinterpret_cast<const bf16x8*>(&Ks[kr * 64 + ((slot ^ (kr & 7)) << 3)]);
        s[n] = MFMA16(aq[h], bk, s[n]);
      }
    bool diag = (jt == last);
#pragma unroll
    for (int n = 0; n < 4; ++n)
#pragma unroll
      for (int r = 0; r < 4; ++r) {
        float sv = s[n][r] * 0.125f;
        if (diag) {
          int kg = j0 + n * 16 + (lane & 15);
          int qg = q0 + wid * 16 + (lane >> 4) * 4 + r;
          if (kg > qg) sv = -INFINITY;
        }
        s[n][r] = sv;
      }
    // --- online softmax (per q-row r; k spread over 16 lanes x 4 frags)
    float rsc[4];
#pragma unroll
    for (int r = 0; r < 4; ++r) {
      float mx = fmaxf(fmaxf(s[0][r], s[1][r]), fmaxf(s[2][r], s[3][r]));
      mx = fmaxf(mx, __shfl_xor(mx, 1, 64));
      mx = fmaxf(mx, __shfl_xor(mx, 2, 64));
      mx = fmaxf(mx, __shfl_xor(mx, 4, 64));
      mx = fmaxf(mx, __shfl_xor(mx, 8, 64));
      float mn = fmaxf(m_r[r], mx);
      rsc[r] = __expf(m_r[r] - mn);
      m_r[r] = mn;
      float ls = 0.f;
#pragma unroll
      for (int n = 0; n < 4; ++n) {
        float p = __expf(s[n][r] - mn);
        s[n][r] = p;
        ls += p;
      }
      ls += __shfl_xor(ls, 1, 64);
      ls += __shfl_xor(ls, 2, 64);
      ls += __shfl_xor(ls, 4, 64);
      ls += __shfl_xor(ls, 8, 64);
      l_r[r] = l_r[r] * rsc[r] + ls;
    }
#pragma unroll
    for (int n = 0; n < 4; ++n)
#pragma unroll
      for (int r = 0; r < 4; ++r) accO[n][r] *= rsc[r];
    // --- P -> per-wave LDS (bf16, swizzled)
    u16* Pw = &Ps[wid][0];
#pragma unroll
    for (int n = 0; n < 4; ++n)
#pragma unroll
      for (int r = 0; r < 4; ++r) {
        int qq = (lane >> 4) * 4 + r;
        int k2 = n * 16 + (lane & 15);
        Pw[qq * 64 + (((k2 >> 3) ^ (qq & 7)) << 3) + (k2 & 7)] = f2b(s[n][r]);
      }
    // --- O += P V
#pragma unroll
    for (int kh = 0; kh < 2; ++kh) {
      int qq = lane & 15;
      int slotp = kh * 4 + (lane >> 4);
      bf16x8 ap = *reinterpret_cast<const bf16x8*>(&Pw[qq * 64 + ((slotp ^ (qq & 7)) << 3)]);
#pragma unroll
      for (int n = 0; n < 4; ++n) {
        int d = n * 16 + (lane & 15);
        bf16x8 bv = *reinterpret_cast<const bf16x8*>(&Vt[d * 64 + ((slotp ^ (d & 7)) << 3)]);
        accO[n] = MFMA16(ap, bv, accO[n]);
      }
    }
  }
#pragma unroll
  for (int r = 0; r < 4; ++r) {
    float inv = 1.f / l_r[r];
    int qg = q0 + wid * 16 + (lane >> 4) * 4 + r;
#pragma unroll
    for (int n = 0; n < 4; ++n)
      O[(size_t)qg * D_MODEL + hoff + n * 16 + (lane & 15)] = f2b(accO[n][r] * inv);
  }
}

// ---------------------------------------------------------------------------
extern "C" void kernel_launch(void* const* d_in, const int* in_sizes, int n_in,
                              void* d_out, int out_size, void* d_ws, size_t ws_size,
                              hipStream_t stream) {
  (void)in_sizes; (void)n_in; (void)out_size; (void)ws_size;
  const float* x   = (const float*)d_in[0];
  const float* ln1 = (const float*)d_in[1];
  const float* ln2 = (const float*)d_in[2];
  const float* wq  = (const float*)d_in[3];
  const float* wk  = (const float*)d_in[4];
  const float* wv  = (const float*)d_in[5];
  const float* wo  = (const float*)d_in[6];
  const float* w1d = (const float*)d_in[7];
  const float* w1u = (const float*)d_in[8];
  const float* w2d = (const float*)d_in[9];
  const float* w2u = (const float*)d_in[10];
  float* out = (float*)d_out;
  char* ws = (char*)d_ws;
  const size_t MB = 1ull << 20;

  u16*   hb   = (u16*)(ws + 0);          // 4 MB  (h, then h2)
  u16*   qb   = (u16*)(ws + 4 * MB);     // 4 MB
  u16*   kb   = (u16*)(ws + 8 * MB);     // 4 MB
  u16*   vb   = (u16*)(ws + 12 * MB);    // 4 MB
  u16*   aob  = (u16*)(ws + 16 * MB);    // 4 MB
  u16*   sb   = (u16*)(ws + 4 * MB);     // 16 MB, reuses q/k/v/ao after step 7
  float* x1   = (float*)(ws + 20 * MB);  // 8 MB
  u16*   abuf = (u16*)(ws + 28 * MB);    // 1 MB
  float* g    = (float*)(ws + 32 * MB);  // 32 MB
  float* g2   = (float*)(ws + 32 * MB);  // 8 MB, reuses g after step 11
  u16*   wqb  = (u16*)(ws + 64 * MB);
  u16*   wkb  = (u16*)(ws + 66 * MB);
  u16*   wvb  = (u16*)(ws + 68 * MB);
  u16*   wob  = (u16*)(ws + 70 * MB);
  u16*   w1ub = (u16*)(ws + 72 * MB);    // 2 MB
  u16*   w2ub = (u16*)(ws + 74 * MB);    // 0.5 MB
  u16*   wt1  = (u16*)(ws + 75 * MB);    // 0.5 MB
  u16*   wt2  = (u16*)(ws + 76 * MB);    // 2 MB  (end: 78 MB)

  dim3 b256(256);
  // weight prep
  conv_bf16_kernel<<<1024, b256, 0, stream>>>(wq, wqb, 262144);
  conv_bf16_kernel<<<1024, b256, 0, stream>>>(wk, wkb, 262144);
  conv_bf16_kernel<<<1024, b256, 0, stream>>>(wv, wvb, 262144);
  conv_bf16_kernel<<<1024, b256, 0, stream>>>(wo, wob, 262144);
  conv_bf16_kernel<<<1024, b256, 0, stream>>>(w1u, w1ub, 262144);
  conv_bf16_kernel<<<256, b256, 0, stream>>>(w2u, w2ub, 65536);
  tr_kernel<<<dim3(16, 4), b256, 0, stream>>>(w1d, wt1, 1024);
  tr_kernel<<<dim3(64, 4), b256, 0, stream>>>(w2d, wt2, 4096);
  // 1. h = rms(x)*ln1 -> bf16
  rms_bf16_kernel<1, false, true><<<T_LEN, b256, 0, stream>>>(x, ln1, hb, 1024);
  // 2. q,k,v
  gemm_qkv_kernel<<<dim3(8, 16, 3), b256, 0, stream>>>(hb, wqb, wkb, wvb, qb, kb, vb, 1024);
  // 3. rope
  rope_bf16_kernel<<<T_LEN, b256, 0, stream>>>(qb, kb);
  // 4. attention
  attn_mfma_kernel<<<dim3(T_LEN / 64, NH), b256, 0, stream>>>(qb, kb, vb, aob);
  // 5. x1 = ao @ wo^T + x
  gemm_res_kernel<<<dim3(8, 16), b256, 0, stream>>>(aob, wob, x1, x, 1024, 1024);
  // 6. h2 = rms(x1)*ln2 -> bf16
  rms_bf16_kernel<1, false, true><<<T_LEN, b256, 0, stream>>>(x1, ln2, hb, 1024);
  // 7. down1 -> abuf
  gemm_bf16_kernel<<<dim3(2, 16), b256, 0, stream>>>(hb, wt1, abuf, 256, 1024);
  // 8. up1 + product -> g
  cache_up_mfma<<<dim3(32, 16), b256, 0, stream>>>(abuf, w1ub, g, 4096);
  // 9. s = silu(rms(g)) -> bf16
  rms_bf16_kernel<4, true, false><<<T_LEN, b256, 0, stream>>>(g, nullptr, sb, 4096);
  // 10. down2 -> abuf
  gemm_bf16_kernel<<<dim3(2, 16), b256, 0, stream>>>(sb, wt2, abuf, 256, 4096);
  // 11. up2 + product -> g2
  cache_up_mfma<<<dim3(8, 16), b256, 0, stream>>>(abuf, w2ub, g2, 1024);
  // 12. out = x1 + rms(g2)
  rms_add_kernel<<<T_LEN, b256, 0, stream>>>(g2, x1, out);
}

// Round 3
// 280.896 us; speedup vs baseline: 4.1388x; 1.4095x over previous
//
#include <hip/hip_runtime.h>
#include <math.h>
#include <stdint.h>

#define T_LEN   2048
#define D_MODEL 1024
#define NH      16
#define DFF     4096

typedef __attribute__((ext_vector_type(8))) short bf16x8;
typedef __attribute__((ext_vector_type(4))) float f32x4;
typedef __attribute__((ext_vector_type(4))) unsigned short u16x4;
typedef __attribute__((ext_vector_type(8))) unsigned short u16x8;
typedef unsigned short u16;

__device__ inline u16 f2b(float x) {
  unsigned int u = __float_as_uint(x);
  unsigned int r = (u + 0x7fffu + ((u >> 16) & 1u)) >> 16;
  return (u16)r;
}
__device__ inline float b2f(u16 h) { return __uint_as_float(((unsigned int)h) << 16); }

typedef const __attribute__((address_space(1))) unsigned int* gas_t;
typedef __attribute__((address_space(3))) unsigned int* las_t;
__device__ inline void gl_lds16(const void* g, void* l) {
  __builtin_amdgcn_global_load_lds((gas_t)g, (las_t)l, 16, 0, 0);
}

#define MFMA16(a, b, c) __builtin_amdgcn_mfma_f32_16x16x32_bf16((a), (b), (c), 0, 0, 0)

// ---------------------------------------------------------------------------
// f32 -> bf16 converts
// ---------------------------------------------------------------------------
__global__ __launch_bounds__(256) void conv_bf16_kernel(
    const float* __restrict__ src, u16* __restrict__ dst, int n4) {
  int i = blockIdx.x * 256 + threadIdx.x;
  if (i < n4) {
    float4 v = reinterpret_cast<const float4*>(src)[i];
    u16x4 o = {f2b(v.x), f2b(v.y), f2b(v.z), f2b(v.w)};
    reinterpret_cast<u16x4*>(dst)[i] = o;
  }
}

__global__ __launch_bounds__(256) void conv4_kernel(
    const float* s0, const float* s1, const float* s2, const float* s3,
    u16* d0, u16* d1, u16* d2, u16* d3, int n4) {
  int z = blockIdx.z;
  const float* s = z == 0 ? s0 : (z == 1 ? s1 : (z == 2 ? s2 : s3));
  u16* d = z == 0 ? d0 : (z == 1 ? d1 : (z == 2 ? d2 : d3));
  int i = blockIdx.x * 256 + threadIdx.x;
  if (i < n4) {
    float4 v = reinterpret_cast<const float4*>(s)[i];
    u16x4 o = {f2b(v.x), f2b(v.y), f2b(v.z), f2b(v.w)};
    reinterpret_cast<u16x4*>(d)[i] = o;
  }
}

// ---------------------------------------------------------------------------
// transpose+convert: w[h][K][64] f32 -> wt[h*64+c][K] bf16.  grid (K/64, 4)
// ---------------------------------------------------------------------------
__global__ __launch_bounds__(256) void tr_kernel(
    const float* __restrict__ w, u16* __restrict__ wt, int K) {
  int k0 = blockIdx.x * 64, h = blockIdx.y;
  __shared__ float Ts[64][65];
  int tid = threadIdx.x;
#pragma unroll
  for (int i = 0; i < 4; ++i) {
    int idx = tid + i * 256;
    int r = idx >> 4, c4 = (idx & 15) * 4;
    float4 v = *reinterpret_cast<const float4*>(w + ((size_t)h * K + k0 + r) * 64 + c4);
    Ts[r][c4 + 0] = v.x; Ts[r][c4 + 1] = v.y; Ts[r][c4 + 2] = v.z; Ts[r][c4 + 3] = v.w;
  }
  __syncthreads();
#pragma unroll
  for (int i = 0; i < 4; ++i) {
    int idx = tid + i * 256;
    int c = idx >> 4, k4 = (idx & 15) * 4;
    u16x4 o = {f2b(Ts[k4 + 0][c]), f2b(Ts[k4 + 1][c]), f2b(Ts[k4 + 2][c]), f2b(Ts[k4 + 3][c])};
    *reinterpret_cast<u16x4*>(wt + (size_t)(h * 64 + c) * K + k0 + k4) = o;
  }
}

// ---------------------------------------------------------------------------
// V transpose: V[t][1024] bf16 -> VT[h*64+d][2048] bf16.  grid (T/64, 16)
// ---------------------------------------------------------------------------
__global__ __launch_bounds__(256) void vtrans_kernel(
    const u16* __restrict__ V, u16* __restrict__ VT) {
  __shared__ u16 Ts[64][72];
  int t0 = blockIdx.x * 64, h = blockIdx.y;
  int tid = threadIdx.x;
#pragma unroll
  for (int it = 0; it < 2; ++it) {
    int c = tid + it * 256;
    int t = c >> 3, d8 = (c & 7) * 8;
    *reinterpret_cast<u16x8*>(&Ts[t][d8]) =
        *reinterpret_cast<const u16x8*>(V + (size_t)(t0 + t) * D_MODEL + h * 64 + d8);
  }
  __syncthreads();
#pragma unroll
  for (int it = 0; it < 2; ++it) {
    int c = tid + it * 256;
    int d = c >> 3, t8 = (c & 7) * 8;
    u16x8 o;
#pragma unroll
    for (int j = 0; j < 8; ++j) o[j] = Ts[t8 + j][d];
    *reinterpret_cast<u16x8*>(VT + ((size_t)h * 64 + d) * T_LEN + t0 + t8) = o;
  }
}

// ---------------------------------------------------------------------------
// RMS f32-in -> bf16 (optional weight).  One row per block.
// ---------------------------------------------------------------------------
template <int NV, bool WEIGHT>
__global__ __launch_bounds__(256) void rms_bf16_kernel(
    const float* __restrict__ in, const float* __restrict__ w,
    u16* __restrict__ out, int width) {
  int row = blockIdx.x, tid = threadIdx.x;
  const float* rp = in + (size_t)row * width;
  float4 vals[NV];
  float ss = 0.f;
#pragma unroll
  for (int v = 0; v < NV; ++v) {
    vals[v] = reinterpret_cast<const float4*>(rp)[v * 256 + tid];
    ss += vals[v].x * vals[v].x + vals[v].y * vals[v].y +
          vals[v].z * vals[v].z + vals[v].w * vals[v].w;
  }
  for (int off = 32; off; off >>= 1) ss += __shfl_down(ss, off, 64);
  __shared__ float wsum[4];
  if ((tid & 63) == 0) wsum[tid >> 6] = ss;
  __syncthreads();
  float tot = wsum[0] + wsum[1] + wsum[2] + wsum[3];
  float scale = rsqrtf(tot / (float)width + 1e-6f);
#pragma unroll
  for (int v = 0; v < NV; ++v) {
    int c4 = v * 256 + tid;
    float o0 = vals[v].x * scale, o1 = vals[v].y * scale,
          o2 = vals[v].z * scale, o3 = vals[v].w * scale;
    if constexpr (WEIGHT) {
      float4 wv = reinterpret_cast<const float4*>(w)[c4];
      o0 *= wv.x; o1 *= wv.y; o2 *= wv.z; o3 *= wv.w;
    }
    u16x4 ov = {f2b(o0), f2b(o1), f2b(o2), f2b(o3)};
    reinterpret_cast<u16x4*>(out + (size_t)row * width)[c4] = ov;
  }
}

// RMS bf16-in width 4096, silu, bf16 out
__global__ __launch_bounds__(256) void rms_silu_bf16_kernel(
    const u16* __restrict__ in, u16* __restrict__ out) {
  int row = blockIdx.x, tid = threadIdx.x;
  const u16* rp = in + (size_t)row * DFF;
  float f[16];
  float ss = 0.f;
#pragma unroll
  for (int v = 0; v < 2; ++v) {
    u16x8 c = reinterpret_cast<const u16x8*>(rp)[v * 256 + tid];
#pragma unroll
    for (int j = 0; j < 8; ++j) {
      float x = b2f((u16)c[j]);
      f[v * 8 + j] = x;
      ss += x * x;
    }
  }
  for (int off = 32; off; off >>= 1) ss += __shfl_down(ss, off, 64);
  __shared__ float wsum[4];
  if ((tid & 63) == 0) wsum[tid >> 6] = ss;
  __syncthreads();
  float tot = wsum[0] + wsum[1] + wsum[2] + wsum[3];
  float scale = rsqrtf(tot / (float)DFF + 1e-6f);
#pragma unroll
  for (int v = 0; v < 2; ++v) {
    u16x8 o;
#pragma unroll
    for (int j = 0; j < 8; ++j) {
      float x = f[v * 8 + j] * scale;
      x = x / (1.f + __expf(-x));
      o[j] = f2b(x);
    }
    reinterpret_cast<u16x8*>(out + (size_t)row * DFF)[v * 256 + tid] = o;
  }
}

// final: out = res + rms(in), width 1024, f32
__global__ __launch_bounds__(256) void rms_add_kernel(
    const float* __restrict__ in, const float* __restrict__ res,
    float* __restrict__ out) {
  int row = blockIdx.x, tid = threadIdx.x;
  float4 v = reinterpret_cast<const float4*>(in + (size_t)row * D_MODEL)[tid];
  float ss = v.x * v.x + v.y * v.y + v.z * v.z + v.w * v.w;
  for (int off = 32; off; off >>= 1) ss += __shfl_down(ss, off, 64);
  __shared__ float wsum[4];
  if ((tid & 63) == 0) wsum[tid >> 6] = ss;
  __syncthreads();
  float tot = wsum[0] + wsum[1] + wsum[2] + wsum[3];
  float scale = rsqrtf(tot / (float)D_MODEL + 1e-6f);
  float4 rv = reinterpret_cast<const float4*>(res + (size_t)row * D_MODEL)[tid];
  float4 o = make_float4(v.x * scale + rv.x, v.y * scale + rv.y,
                         v.z * scale + rv.z, v.w * scale + rv.w);
  reinterpret_cast<float4*>(out + (size_t)row * D_MODEL)[tid] = o;
}

// ---------------------------------------------------------------------------
// bf16 NT GEMM core: C[128x128 tile] = A[M,lda] * B[N,lda]^T over Kloop.
// OUT: 0 = bf16, 1 = f32 + res, 2 = f32 partial
// ---------------------------------------------------------------------------
template <int OUT>
__device__ inline void gemm_nt_body(const u16* A, const u16* B, void* Cv,
                                    const float* RES, int N, int lda, int Kloop,
                                    int row0, int col0) {
  __shared__ __align__(16) u16 As[128 * 32];
  __shared__ __align__(16) u16 Bs[128 * 32];
  int tid = threadIdx.x, lane = tid & 63, wid = tid >> 6;
  int wr = wid >> 1, wc = wid & 1;
  const f32x4 fz = {0.f, 0.f, 0.f, 0.f};
  f32x4 acc[4][4];
#pragma unroll
  for (int m = 0; m < 4; ++m)
#pragma unroll
    for (int n = 0; n < 4; ++n) acc[m][n] = fz;

  for (int k0 = 0; k0 < Kloop; k0 += 32) {
    __syncthreads();
#pragma unroll
    for (int i = 0; i < 2; ++i) {
      int wl = wid * 2 + i;
      int row = wl * 16 + (lane >> 2);
      int col8 = ((lane & 3) ^ (row & 3)) * 8;
      gl_lds16(A + (size_t)(row0 + row) * lda + k0 + col8, &As[wl * 512]);
      gl_lds16(B + (size_t)(col0 + row) * lda + k0 + col8, &Bs[wl * 512]);
    }
    __syncthreads();
    bf16x8 af[4], bfr[4];
#pragma unroll
    for (int m = 0; m < 4; ++m) {
      int r = wr * 64 + m * 16 + (lane & 15);
      af[m] = *reinterpret_cast<const bf16x8*>(&As[r * 32 + (((lane >> 4) ^ (r & 3)) << 3)]);
    }
#pragma unroll
    for (int n = 0; n < 4; ++n) {
      int r = wc * 64 + n * 16 + (lane & 15);
      bfr[n] = *reinterpret_cast<const bf16x8*>(&Bs[r * 32 + (((lane >> 4) ^ (r & 3)) << 3)]);
    }
#pragma unroll
    for (int m = 0; m < 4; ++m)
#pragma unroll
      for (int n = 0; n < 4; ++n) acc[m][n] = MFMA16(af[m], bfr[n], acc[m][n]);
  }
#pragma unroll
  for (int m = 0; m < 4; ++m)
#pragma unroll
    for (int n = 0; n < 4; ++n)
#pragma unroll
      for (int r = 0; r < 4; ++r) {
        int grow = row0 + wr * 64 + m * 16 + (lane >> 4) * 4 + r;
        int gcol = col0 + wc * 64 + n * 16 + (lane & 15);
        float v = acc[m][n][r];
        if constexpr (OUT == 0) {
          ((u16*)Cv)[(size_t)grow * N + gcol] = f2b(v);
        } else if constexpr (OUT == 1) {
          ((float*)Cv)[(size_t)grow * N + gcol] = v + RES[(size_t)grow * N + gcol];
        } else {
          ((float*)Cv)[(size_t)grow * N + gcol] = v;
        }
      }
}

__global__ __launch_bounds__(256) void gemm_qkv_kernel(
    const u16* __restrict__ A, const u16* Bq, const u16* Bk, const u16* Bv,
    u16* Cq, u16* Ck, u16* Cvp) {
  const u16* B = blockIdx.z == 0 ? Bq : (blockIdx.z == 1 ? Bk : Bv);
  u16* C = blockIdx.z == 0 ? Cq : (blockIdx.z == 1 ? Ck : Cvp);
  gemm_nt_body<0>(A, B, C, nullptr, D_MODEL, D_MODEL, D_MODEL,
                  blockIdx.y * 128, blockIdx.x * 128);
}
__global__ __launch_bounds__(256) void gemm_res_kernel(
    const u16* __restrict__ A, const u16* __restrict__ B, float* __restrict__ C,
    const float* __restrict__ RES) {
  gemm_nt_body<1>(A, B, C, RES, D_MODEL, D_MODEL, D_MODEL,
                  blockIdx.y * 128, blockIdx.x * 128);
}
// split-K down-proj: Cp[z][2048][256] partials, grid (2, 16, SPLIT)
__global__ __launch_bounds__(256) void gemm_splitk_kernel(
    const u16* __restrict__ A, const u16* __restrict__ B, float* __restrict__ Cp,
    int lda, int Kchunk) {
  int z = blockIdx.z;
  gemm_nt_body<2>(A + (size_t)z * Kchunk, B + (size_t)z * Kchunk,
                  Cp + (size_t)z * (T_LEN * 256), nullptr, 256, lda, Kchunk,
                  blockIdx.y * 128, blockIdx.x * 128);
}
// reduce partials + convert to bf16
__global__ __launch_bounds__(256) void reduce_conv_kernel(
    const float* __restrict__ part, u16* __restrict__ out, int n4, int nsplit) {
  int i = blockIdx.x * 256 + threadIdx.x;
  if (i >= n4) return;
  float4 a = reinterpret_cast<const float4*>(part)[i];
  for (int s = 1; s < nsplit; ++s) {
    float4 b = reinterpret_cast<const float4*>(part)[i + (size_t)s * n4];
    a.x += b.x; a.y += b.y; a.z += b.z; a.w += b.w;
  }
  u16x4 o = {f2b(a.x), f2b(a.y), f2b(a.z), f2b(a.w)};
  reinterpret_cast<u16x4*>(out)[i] = o;
}

// ---------------------------------------------------------------------------
// cache up-proj + product: G[t][o] = prod_h dot64(A[t][h*64+:], UP[h][o][:])
// ---------------------------------------------------------------------------
template <bool BF16_OUT>
__global__ __launch_bounds__(256) void cache_up_mfma(
    const u16* __restrict__ Acoef, const u16* __restrict__ UP,
    void* __restrict__ Gv, int N) {
  __shared__ __align__(16) u16 As[128 * 64];
  __shared__ __align__(16) u16 Bs[128 * 64];
  int tid = threadIdx.x, lane = tid & 63, wid = tid >> 6;
  int wr = wid >> 1, wc = wid & 1;
  int row0 = blockIdx.y * 128, col0 = blockIdx.x * 128;
  const f32x4 fz = {0.f, 0.f, 0.f, 0.f};
  f32x4 prod[4][4];
#pragma unroll
  for (int m = 0; m < 4; ++m)
#pragma unroll
    for (int n = 0; n < 4; ++n) prod[m][n] = fz + 1.f;

  for (int h = 0; h < 4; ++h) {
    __syncthreads();
#pragma unroll
    for (int i = 0; i < 4; ++i) {
      int wl = wid * 4 + i;
      int row = wl * 8 + (lane >> 3);
      int col8 = ((lane & 7) ^ (row & 7)) * 8;
      gl_lds16(Acoef + (size_t)(row0 + row) * 256 + h * 64 + col8, &As[wl * 512]);
      gl_lds16(UP + ((size_t)h * N + col0 + row) * 64 + col8, &Bs[wl * 512]);
    }
    __syncthreads();
    f32x4 d[4][4];
#pragma unroll
    for (int m = 0; m < 4; ++m)
#pragma unroll
      for (int n = 0; n < 4; ++n) d[m][n] = fz;
#pragma unroll
    for (int kh = 0; kh < 2; ++kh) {
      bf16x8 af[4], bfr[4];
#pragma unroll
      for (int m = 0; m < 4; ++m) {
        int r = wr * 64 + m * 16 + (lane & 15);
        int slot = kh * 4 + (lane >> 4);
        af[m] = *reinterpret_cast<const bf16x8*>(&As[r * 64 + ((slot ^ (r & 7)) << 3)]);
      }
#pragma unroll
      for (int n = 0; n < 4; ++n) {
        int r = wc * 64 + n * 16 + (lane & 15);
        int slot = kh * 4 + (lane >> 4);
        bfr[n] = *reinterpret_cast<const bf16x8*>(&Bs[r * 64 + ((slot ^ (r & 7)) << 3)]);
      }
#pragma unroll
      for (int m = 0; m < 4; ++m)
#pragma unroll
        for (int n = 0; n < 4; ++n) d[m][n] = MFMA16(af[m], bfr[n], d[m][n]);
    }
#pragma unroll
    for (int m = 0; m < 4; ++m)
#pragma unroll
      for (int n = 0; n < 4; ++n) prod[m][n] *= d[m][n];
  }
#pragma unroll
  for (int m = 0; m < 4; ++m)
#pragma unroll
    for (int n = 0; n < 4; ++n)
#pragma unroll
      for (int r = 0; r < 4; ++r) {
        int grow = row0 + wr * 64 + m * 16 + (lane >> 4) * 4 + r;
        int gcol = col0 + wc * 64 + n * 16 + (lane & 15);
        if constexpr (BF16_OUT)
          ((u16*)Gv)[(size_t)grow * N + gcol] = f2b(prod[m][n][r]);
        else
          ((float*)Gv)[(size_t)grow * N + gcol] = prod[m][n][r];
      }
}

// ---------------------------------------------------------------------------
// RoPE in place on bf16 q,k
// ---------------------------------------------------------------------------
__global__ __launch_bounds__(256) void rope_bf16_kernel(u16* __restrict__ q,
                                                        u16* __restrict__ k) {
  int t = blockIdx.x, tid = threadIdx.x;
  const float NEG = -0.28782313662425573f;  // -ln(10000)/32
#pragma unroll
  for (int u = 0; u < 2; ++u) {
    int p = tid + u * 256;
    int i = p & 31;
    int col = (p >> 5) * 64 + 2 * i;
    float ang = (float)t * __expf(NEG * (float)i);
    float sv, cv;
    __sincosf(ang, &sv, &cv);
    size_t idx = (size_t)t * D_MODEL + col;
    unsigned int* qp = reinterpret_cast<unsigned int*>(q + idx);
    unsigned int qv = *qp;
    float q1 = b2f(qv & 0xffff), q2 = b2f(qv >> 16);
    *qp = (unsigned int)f2b(q1 * cv - q2 * sv) |
          ((unsigned int)f2b(q1 * sv + q2 * cv) << 16);
    unsigned int* kp = reinterpret_cast<unsigned int*>(k + idx);
    unsigned int kv = *kp;
    float k1 = b2f(kv & 0xffff), k2 = b2f(kv >> 16);
    *kp = (unsigned int)f2b(k1 * cv - k2 * sv) |
          ((unsigned int)f2b(k1 * sv + k2 * cv) << 16);
  }
}

// ---------------------------------------------------------------------------
// MFMA flash attention, causal, swapped-QK^T + in-register P.
// 128 threads = 2 waves; 32 q-rows per block (16/wave); KV tile 64.
// grid (T/32, NH), q-tile order reversed for load balance.
// ---------------------------------------------------------------------------
__global__ __launch_bounds__(128) void attn_mfma_kernel(
    const u16* __restrict__ Q, const u16* __restrict__ Kb,
    const u16* __restrict__ VT, u16* __restrict__ O) {
  __shared__ __align__(16) u16 Ks[64 * 64];
  __shared__ __align__(16) u16 Vt[64 * 64];
  int tid = threadIdx.x, lane = tid & 63, wid = tid >> 6;
  int G = lane >> 4, ql = lane & 15;
  int head = blockIdx.y, hoff = head * 64;
  int qt = (int)gridDim.x - 1 - (int)blockIdx.x;
  int q0 = qt * 32;
  int qg = q0 + wid * 16 + ql;  // this lane's q-row (S^T layout)

  bf16x8 aq[2];
  {
    const u16* qp = Q + (size_t)qg * D_MODEL + hoff + G * 8;
    aq[0] = *reinterpret_cast<const bf16x8*>(qp);
    aq[1] = *reinterpret_cast<const bf16x8*>(qp + 32);
  }
  const f32x4 fz = {0.f, 0.f, 0.f, 0.f};
  f32x4 accO[4];
#pragma unroll
  for (int n = 0; n < 4; ++n) accO[n] = fz;
  float m_p = -INFINITY, l_p = 0.f;

  int ntile = (q0 + 31) / 64 + 1;
  for (int jt = 0; jt < ntile; ++jt) {
    int j0 = jt * 64;
    __syncthreads();
#pragma unroll
    for (int i = 0; i < 4; ++i) {
      int wl = wid * 4 + i;
      int row = wl * 8 + (lane >> 3);
      int col8 = ((lane & 7) ^ (row & 7)) * 8;
      gl_lds16(Kb + (size_t)(j0 + row) * D_MODEL + hoff + col8, &Ks[wl * 512]);
      gl_lds16(VT + ((size_t)hoff + row) * T_LEN + j0 + col8, &Vt[wl * 512]);
    }
    __syncthreads();
    // ---- S^T = K Q^T : lane holds q=ql, k = n*16 + 4G + r
    f32x4 s[4];
#pragma unroll
    for (int n = 0; n < 4; ++n) s[n] = fz;
#pragma unroll
    for (int n = 0; n < 4; ++n) {
      int kr = n * 16 + ql;
#pragma unroll
      for (int h = 0; h < 2; ++h) {
        int slot = (h * 4 + G) ^ (kr & 7);
        bf16x8 bk = *reinterpret_cast<const bf16x8*>(&Ks[kr * 64 + slot * 8]);
        s[n] = MFMA16(bk, aq[h], s[n]);
      }
    }
    bool diag = (jt == ntile - 1);
#pragma unroll
    for (int n = 0; n < 4; ++n)
#pragma unroll
      for (int r = 0; r < 4; ++r) {
        float sv = s[n][r] * 0.125f;
        if (diag && (j0 + n * 16 + 4 * G + r > qg)) sv = -INFINITY;
        s[n][r] = sv;
      }
    // ---- online softmax, lane-local in q
    float mx = s[0][0];
#pragma unroll
    for (int n = 0; n < 4; ++n)
#pragma unroll
      for (int r = 0; r < 4; ++r) mx = fmaxf(mx, s[n][r]);
    mx = fmaxf(mx, __shfl_xor(mx, 16, 64));
    mx = fmaxf(mx, __shfl_xor(mx, 32, 64));
    float mn = fmaxf(m_p, mx);
    float rsc = __expf(m_p - mn);
    m_p = mn;
    float ls = 0.f;
#pragma unroll
    for (int n = 0; n < 4; ++n)
#pragma unroll
      for (int r = 0; r < 4; ++r) {
        float p = __expf(s[n][r] - mn);
        s[n][r] = p;
        ls += p;
      }
    ls += __shfl_xor(ls, 16, 64);
    ls += __shfl_xor(ls, 32, 64);
    l_p = l_p * rsc + ls;
    // ---- pack P to bf16 pairs: w32[n][rr] = {k=16n+4G+2rr, +1} for q=ql
    unsigned int w32[4][2];
#pragma unroll
    for (int n = 0; n < 4; ++n)
#pragma unroll
      for (int rr = 0; rr < 2; ++rr) {
        unsigned int pk;
        asm("v_cvt_pk_bf16_f32 %0, %1, %2"
            : "=v"(pk) : "v"(s[n][2 * rr]), "v"(s[n][2 * rr + 1]));
        w32[n][rr] = pk;
      }
    // ---- rescale accO (O rows are q = 4G + r)
    float rscx[4];
#pragma unroll
    for (int r = 0; r < 4; ++r) rscx[r] = __shfl(rsc, 4 * G + r, 64);
#pragma unroll
    for (int n = 0; n < 4; ++n)
#pragma unroll
      for (int r = 0; r < 4; ++r) accO[n][r] *= rscx[r];
    // ---- PV: assemble A-frag (q=ql, k=kh*32+8G+j) via cross-lane exchange
#pragma unroll
    for (int kh = 0; kh < 2; ++kh) {
      union { unsigned int w[4]; bf16x8 v; } ap;
#pragma unroll
      for (int w = 0; w < 4; ++w) {
        int src = ql + (((2 * G + (w >> 1)) & 3) << 4);
        unsigned int v0 = (unsigned int)__shfl((int)w32[2 * kh][w & 1], src, 64);
        unsigned int v1 = (unsigned int)__shfl((int)w32[2 * kh + 1][w & 1], src, 64);
        ap.w[w] = (G >> 1) ? v1 : v0;
      }
#pragma unroll
      for (int n = 0; n < 4; ++n) {
        int d = n * 16 + ql;
        int slot = (kh * 4 + G) ^ (d & 7);
        bf16x8 bv = *reinterpret_cast<const bf16x8*>(&Vt[d * 64 + slot * 8]);
        accO[n] = MFMA16(ap.v, bv, accO[n]);
      }
    }
  }
  float invl = 1.f / l_p;
  float linvx[4];
#pragma unroll
  for (int r = 0; r < 4; ++r) linvx[r] = __shfl(invl, 4 * G + r, 64);
#pragma unroll
  for (int n = 0; n < 4; ++n)
#pragma unroll
    for (int r = 0; r < 4; ++r) {
      int qrow = q0 + wid * 16 + 4 * G + r;
      O[(size_t)qrow * D_MODEL + hoff + n * 16 + ql] = f2b(accO[n][r] * linvx[r]);
    }
}

// ---------------------------------------------------------------------------
extern "C" void kernel_launch(void* const* d_in, const int* in_sizes, int n_in,
                              void* d_out, int out_size, void* d_ws, size_t ws_size,
                              hipStream_t stream) {
  (void)in_sizes; (void)n_in; (void)out_size; (void)ws_size;
  const float* x   = (const float*)d_in[0];
  const float* ln1 = (const float*)d_in[1];
  const float* ln2 = (const float*)d_in[2];
  const float* wq  = (const float*)d_in[3];
  const float* wk  = (const float*)d_in[4];
  const float* wv  = (const float*)d_in[5];
  const float* wo  = (const float*)d_in[6];
  const float* w1d = (const float*)d_in[7];
  const float* w1u = (const float*)d_in[8];
  const float* w2d = (const float*)d_in[9];
  const float* w2u = (const float*)d_in[10];
  float* out = (float*)d_out;
  char* ws = (char*)d_ws;
  const size_t HMB = 1ull << 19;  // 0.5 MB

  u16*   wqb  = (u16*)(ws + 0 * HMB);
  u16*   wkb  = (u16*)(ws + 4 * HMB);
  u16*   wvb  = (u16*)(ws + 8 * HMB);
  u16*   wob  = (u16*)(ws + 12 * HMB);
  u16*   w1ub = (u16*)(ws + 16 * HMB);   // 2 MB
  u16*   w2ub = (u16*)(ws + 20 * HMB);   // 0.5 MB
  u16*   wt1  = (u16*)(ws + 21 * HMB);   // 0.5 MB
  u16*   wt2  = (u16*)(ws + 22 * HMB);   // 2 MB -> ends 13 MB
  u16*   hb   = (u16*)(ws + 26 * HMB);   // 4 MB -> 17
  float* x1   = (float*)(ws + 34 * HMB); // 8 MB -> 25
  u16*   abuf = (u16*)(ws + 50 * HMB);   // 1 MB -> 26
  u16*   qb   = (u16*)(ws + 52 * HMB);   // 4 MB -> 30
  u16*   kb   = (u16*)(ws + 60 * HMB);   // 4 MB -> 34
  u16*   vb   = (u16*)(ws + 68 * HMB);   // 4 MB -> 38
  u16*   vtb  = (u16*)(ws + 76 * HMB);   // 4 MB -> 42
  u16*   aob  = (u16*)(ws + 84 * HMB);   // 4 MB -> 46
  u16*   g    = (u16*)(ws + 52 * HMB);   // 16 MB bf16, reuses qb..vtb (26..42)
  float* g2   = (float*)(ws + 52 * HMB); // 8 MB f32, after g dead
  u16*   sb   = (u16*)(ws + 84 * HMB);   // 16 MB, reuses aob.. (42..58)
  float* part = (float*)(ws + 116 * HMB);// up to 16 MB (58..74)

  dim3 b256(256), b128(128);
  // weight prep
  conv4_kernel<<<dim3(1024, 1, 4), b256, 0, stream>>>(wq, wk, wv, wo,
                                                      wqb, wkb, wvb, wob, 262144);
  conv_bf16_kernel<<<1024, b256, 0, stream>>>(w1u, w1ub, 262144);
  conv_bf16_kernel<<<256, b256, 0, stream>>>(w2u, w2ub, 65536);
  tr_kernel<<<dim3(16, 4), b256, 0, stream>>>(w1d, wt1, 1024);
  tr_kernel<<<dim3(64, 4), b256, 0, stream>>>(w2d, wt2, 4096);
  // 1. h = rms(x)*ln1 -> bf16
  rms_bf16_kernel<1, true><<<T_LEN, b256, 0, stream>>>(x, ln1, hb, 1024);
  // 2. q,k,v
  gemm_qkv_kernel<<<dim3(8, 16, 3), b256, 0, stream>>>(hb, wqb, wkb, wvb, qb, kb, vb);
  // 3. rope + V transpose
  rope_bf16_kernel<<<T_LEN, b256, 0, stream>>>(qb, kb);
  vtrans_kernel<<<dim3(32, 16), b256, 0, stream>>>(vb, vtb);
  // 4. attention
  attn_mfma_kernel<<<dim3(T_LEN / 32, NH), b128, 0, stream>>>(qb, kb, vtb, aob);
  // 5. x1 = ao @ wo^T + x
  gemm_res_kernel<<<dim3(8, 16), b256, 0, stream>>>(aob, wob, x1, x);
  // 6. h2 = rms(x1)*ln2 -> bf16
  rms_bf16_kernel<1, true><<<T_LEN, b256, 0, stream>>>(x1, ln2, hb, 1024);
  // 7. down1 (split-K 4) -> abuf
  gemm_splitk_kernel<<<dim3(2, 16, 4), b256, 0, stream>>>(hb, wt1, part, 1024, 256);
  reduce_conv_kernel<<<512, b256, 0, stream>>>(part, abuf, 131072, 4);
  // 8. up1 + product -> g (bf16)
  cache_up_mfma<true><<<dim3(32, 16), b256, 0, stream>>>(abuf, w1ub, g, 4096);
  // 9. s = silu(rms(g)) -> sb
  rms_silu_bf16_kernel<<<T_LEN, b256, 0, stream>>>(g, sb);
  // 10. down2 (split-K 8) -> abuf
  gemm_splitk_kernel<<<dim3(2, 16, 8), b256, 0, stream>>>(sb, wt2, part, 4096, 512);
  reduce_conv_kernel<<<512, b256, 0, stream>>>(part, abuf, 131072, 8);
  // 11. up2 + product -> g2 (f32)
  cache_up_mfma<false><<<dim3(8, 16), b256, 0, stream>>>(abuf, w2ub, g2, 1024);
  // 12. out = x1 + rms(g2)
  rms_add_kernel<<<T_LEN, b256, 0, stream>>>(g2, x1, out);
}